// Round 5
// baseline (2373.519 us; speedup 1.0000x reference)
//
#include <hip/hip_runtime.h>
#include <math.h>
#include <stdint.h>

// Problem constants
#define BB   32     // batch
#define HB   16     // batch per block (b-split: 2 blocks per n-group)
#define NN   2048   // input capsules
#define KK   16     // input dim
#define CC   32     // output capsules
#define DD   32     // capsule dim
#define NCOL 1024   // CC*DD
#define NPB  8      // n per block -> 256 n-groups x 2 b-halves = 512 blocks (2/CU)
#define WT   (KK * NCOL)          // 16384 floats = one 64 KB W tile
#define OSZ  (BB * NCOL)          // 32768 floats = one full o/partial image
#define NGRP (NN / NPB)           // 256 partial images
#define NSLICE 8                  // reduce tree fan-in stage 1: 256 -> 8

// Ladder (R0..R4):
//  - 1024-thr blocks: hard 64-VGPR pin. Any structure needing more spills
//    (R1 86MB / R2 1.3GB / R4 2GB scratch traffic). Confirmed 4x.
//  - LDS-staged W serializes on barrier-coupled DMA (R0: 95us at 2 blk/CU;
//    R3 dbuf at 1 blk/CU: 148us). W has NO intra-block temporal reuse, so
//    LDS staging is pure overhead.
//  - R4 (direct W loads @1024thr) proved the load path streams (3.7 TB/s)
//    but the in-flight w float4s + 32 acc floats don't fit in 64 VGPR.
// R5 (this): the untried cell — direct W loads at 512 threads with
// __launch_bounds__(512,4): VGPR capped at 128 (R3 proved this acc shape
// fits 128 clean), 2 blocks/CU = 16 waves/CU of plain pipelined
// global_load_dwordx4. No DMA, no vmcnt choreography. Compiler limits its
// own load-hoist depth to the cap instead of spilling.
// XCD pairing: blocks g, g+256 (same W rows) -> same XCD (256%8==0).
__global__ __launch_bounds__(512, 4)
void caps_stage(const float* __restrict__ u, const float* __restrict__ W,
                const float* __restrict__ onorm, float* __restrict__ part)
{
    __shared__ float ush[NPB * KK * HB];     // 8 KB: [n][k][b] all 8 n's
    __shared__ float logit_sh[HB * CC];      // 2 KB
    __shared__ float c_sh[HB * CC];          // 2 KB

    const int tid  = threadIdx.x;
    const int bg = tid >> 8;          // 0..1 -> 8 local b's each
    const int cq = tid & 255;         // col-quad 0..255
    const int i0 = cq >> 3;           // capsule 0..31
    const int jq = cq & 7;            // d-quad
    const int b0 = bg << 3;           // local b base (0 or 8)
    const int c0 = cq << 2;           // col base

    const int ngrp  = blockIdx.x & 255;
    const int bhalf = blockIdx.x >> 8;
    const int n0    = ngrp * NPB;
    const int bbase = bhalf * HB;     // global b offset

    // prologue: stage u for this block (8 KB, transposed [n][k][b])
    for (int idx = tid; idx < NPB * KK * HB; idx += 512) {
        const int n = idx >> 8, rem = idx & 255, k = rem >> 4, b = rem & 15;
        ush[idx] = u[(size_t)(bbase + b) * (NN * KK) + (size_t)(n0 + n) * KK + k];
    }
    __syncthreads();

    // per-thread W column base: W[n0][0][c0..c0+3]
    const float* wp = W + (size_t)n0 * WT + c0;

    float opart[8][4];
#pragma unroll
    for (int bb = 0; bb < 8; ++bb)
#pragma unroll
        for (int m = 0; m < 4; ++m) opart[bb][m] = 0.f;

    for (int nn = 0; nn < NPB; ++nn) {
        const float* un = &ush[nn << 8];

        float accU[8][4];
#pragma unroll
        for (int bb = 0; bb < 8; ++bb)
#pragma unroll
            for (int m = 0; m < 4; ++m) accU[bb][m] = 0.f;

#pragma unroll
        for (int k = 0; k < KK; ++k) {
            const float4 w  = *(const float4*)(wp + k * NCOL);  // global, coalesced
            // LDS broadcast reads (same addr across the wave -> free)
            const float4 ua = *(const float4*)&un[(k << 4) + b0];
            const float4 ub = *(const float4*)&un[(k << 4) + b0 + 4];
            float us[8];
            us[0] = ua.x; us[1] = ua.y; us[2] = ua.z; us[3] = ua.w;
            us[4] = ub.x; us[5] = ub.y; us[6] = ub.z; us[7] = ub.w;
#pragma unroll
            for (int bb = 0; bb < 8; ++bb) {
                accU[bb][0] = fmaf(us[bb], w.x, accU[bb][0]);
                accU[bb][1] = fmaf(us[bb], w.y, accU[bb][1]);
                accU[bb][2] = fmaf(us[bb], w.z, accU[bb][2]);
                accU[bb][3] = fmaf(us[bb], w.w, accU[bb][3]);
            }
        }
        wp += WT;   // next n's tile

        // ---- logits: dot with onorm (L2-resident), reduce over jq lanes ----
#pragma unroll
        for (int bb = 0; bb < 8; ++bb) {
            const float4 on4 = *(const float4*)(
                onorm + ((size_t)(bbase + b0 + bb) * CC + i0) * DD + (jq << 2));
            float p = accU[bb][0] * on4.x + accU[bb][1] * on4.y
                    + accU[bb][2] * on4.z + accU[bb][3] * on4.w;
            p += __shfl_xor(p, 1);
            p += __shfl_xor(p, 2);
            p += __shfl_xor(p, 4);
            if (jq == 0)
                logit_sh[(b0 + bb) * CC + i0] = p;
        }
        __syncthreads();   // (B) logits ready

        // ---- softmax over capsules: all 512 threads, (b = tid>>5, cap = tid&31) ----
        {
            const int b  = tid >> 5;
            const int ii = tid & 31;
            float l = logit_sh[b * CC + ii];
            float mx = l;
#pragma unroll
            for (int msk = 16; msk >= 1; msk >>= 1)
                mx = fmaxf(mx, __shfl_xor(mx, msk));
            const float e = __expf(l - mx);
            float sm = e;
#pragma unroll
            for (int msk = 16; msk >= 1; msk >>= 1)
                sm += __shfl_xor(sm, msk);
            c_sh[b * CC + ii] = e / sm;
        }
        __syncthreads();   // (C) c ready

        // ---- opart += c * U ----
#pragma unroll
        for (int bb = 0; bb < 8; ++bb) {
            const float cc = c_sh[(b0 + bb) * CC + i0];
#pragma unroll
            for (int m = 0; m < 4; ++m)
                opart[bb][m] = fmaf(cc, accU[bb][m], opart[bb][m]);
        }
    }

    // flush partials, coalesced float4 stores (this block's 16-b half)
    float* my = part + (size_t)ngrp * OSZ + (size_t)bbase * NCOL;
#pragma unroll
    for (int bb = 0; bb < 8; ++bb) {
        float4 v;
        v.x = opart[bb][0]; v.y = opart[bb][1];
        v.z = opart[bb][2]; v.w = opart[bb][3];
        *(float4*)&my[(b0 + bb) * NCOL + c0] = v;
    }
}

// Level-1 reduce: 256 partial images -> NSLICE slice images (32 each).
__global__ __launch_bounds__(256) void caps_reduce1(
    const float* __restrict__ part, float* __restrict__ ws2)
{
    const int gid   = blockIdx.x * 256 + threadIdx.x;     // 0..65535
    const int slice = gid >> 13;                          // 0..7
    const int q     = gid & 8191;                         // col-quad
    float4 acc = make_float4(0.f, 0.f, 0.f, 0.f);
    const float* p = part + ((size_t)slice * 32) * OSZ + (q << 2);
#pragma unroll 8
    for (int j = 0; j < 32; ++j) {
        const float4 v = *(const float4*)(p + (size_t)j * OSZ);
        acc.x += v.x; acc.y += v.y; acc.z += v.z; acc.w += v.w;
    }
    *(float4*)(ws2 + ((size_t)gid << 2)) = acc;
}

// Level-2 reduce + row op. mode 0: l2-normalize. mode 1: squash.
__global__ __launch_bounds__(256) void caps_reduce2(
    const float* __restrict__ ws2, float* __restrict__ dst, int mode)
{
    const int q = blockIdx.x * 256 + threadIdx.x;         // 0..8191
    float4 acc = make_float4(0.f, 0.f, 0.f, 0.f);
#pragma unroll
    for (int s = 0; s < NSLICE; ++s) {
        const float4 v = *(const float4*)(ws2 + ((size_t)s << 15) + (q << 2));
        acc.x += v.x; acc.y += v.y; acc.z += v.z; acc.w += v.w;
    }
    float s2 = acc.x * acc.x + acc.y * acc.y + acc.z * acc.z + acc.w * acc.w;
    s2 += __shfl_xor(s2, 1);
    s2 += __shfl_xor(s2, 2);
    s2 += __shfl_xor(s2, 4);
    float scale;
    if (mode == 0) {
        scale = rsqrtf(fmaxf(s2, 1e-12f));
    } else {
        scale = (s2 / (1.f + s2)) / sqrtf(s2 + 1e-7f);
    }
    float4 o;
    o.x = acc.x * scale; o.y = acc.y * scale;
    o.z = acc.z * scale; o.w = acc.w * scale;
    *(float4*)(dst + ((size_t)q << 2)) = o;
}

extern "C" void kernel_launch(void* const* d_in, const int* in_sizes, int n_in,
                              void* d_out, int out_size, void* d_ws, size_t ws_size,
                              hipStream_t stream)
{
    const float* u = (const float*)d_in[0];   // (32, 2048, 16)
    const float* W = (const float*)d_in[1];   // (2048, 16, 1024)
    float* out = (float*)d_out;               // (32, 32, 32)

    // ws layout: part (256*32768 fl = 32 MB) | ws2 (1 MB) | onorm (128 KB)
    float* part  = (float*)d_ws;
    float* ws2   = part + (size_t)NGRP * OSZ;
    float* onorm = ws2 + (size_t)NSLICE * OSZ;

    // onorm = 0 => logits 0 => softmax uniform 1/32 (exactly iteration 0)
    hipMemsetAsync(onorm, 0, (size_t)OSZ * sizeof(float), stream);

    for (int it = 0; it < 3; ++it) {
        caps_stage<<<2 * NGRP, 512, 0, stream>>>(u, W, onorm, part);
        caps_reduce1<<<256, 256, 0, stream>>>(part, ws2);
        if (it < 2)
            caps_reduce2<<<32, 256, 0, stream>>>(ws2, onorm, 0);  // l2-normalize
        else
            caps_reduce2<<<32, 256, 0, stream>>>(ws2, out, 1);    // squash -> d_out
    }
}

// Round 6
// 658.665 us; speedup vs baseline: 3.6035x; 3.6035x over previous
//
#include <hip/hip_runtime.h>
#include <math.h>
#include <stdint.h>

// Problem constants
#define BB   32     // batch
#define HB   16     // batch per block (b-split: 2 blocks per n-group)
#define NN   2048   // input capsules
#define KK   16     // input dim
#define CC   32     // output capsules
#define DD   32     // capsule dim
#define NCOL 1024   // CC*DD
#define NPB  8      // n per block -> 256 n-groups x 2 b-halves = 512 blocks
#define WT   (KK * NCOL)          // 16384 floats = one 64 KB W tile
#define OSZ  (BB * NCOL)          // 32768 floats = one full o/partial image
#define NGRP (NN / NPB)           // 256 partial images
#define NSLICE 8                  // reduce tree fan-in stage 1: 256 -> 8

// Ladder (R0..R5):
//  - 1024-thr blocks: hard 64-VGPR pin (4x confirmed). Structures needing
//    more spill GB/stage of scratch.
//  - LDS-staging W is pure overhead (no intra-block reuse) and its barrier-
//    coupled DMA serializes (R0 95us, R3 148us).
//  - R4/R5: direct-W k-loop needs ~115 VGPR; at 64 it spills. R5's
//    __launch_bounds__(512,4) FAILED to raise the cap (compiler resolved to
//    64). The only spelling that measurably produced 128 VGPR is R3's:
//    __launch_bounds__(512) + amdgpu_waves_per_eu(2).
// R6 (this): R5's kernel with that exact attribute spelling. 12 KB LDS,
// 128 VGPR -> 4 waves/SIMD = 2 blocks/CU co-resident. Direct coalesced
// float4 W loads (lanes cq,cq+1 -> consecutive 16 B), compiler-pipelined.
// XCD pairing: blocks g, g+256 (same W rows) -> same XCD (256%8==0).
__global__ __launch_bounds__(512) __attribute__((amdgpu_waves_per_eu(2)))
void caps_stage(const float* __restrict__ u, const float* __restrict__ W,
                const float* __restrict__ onorm, float* __restrict__ part)
{
    __shared__ float ush[NPB * KK * HB];     // 8 KB: [n][k][b] all 8 n's
    __shared__ float logit_sh[HB * CC];      // 2 KB
    __shared__ float c_sh[HB * CC];          // 2 KB

    const int tid  = threadIdx.x;
    const int bg = tid >> 8;          // 0..1 -> 8 local b's each
    const int cq = tid & 255;         // col-quad 0..255
    const int i0 = cq >> 3;           // capsule 0..31
    const int jq = cq & 7;            // d-quad
    const int b0 = bg << 3;           // local b base (0 or 8)
    const int c0 = cq << 2;           // col base

    const int ngrp  = blockIdx.x & 255;
    const int bhalf = blockIdx.x >> 8;
    const int n0    = ngrp * NPB;
    const int bbase = bhalf * HB;     // global b offset

    // prologue: stage u for this block (8 KB, transposed [n][k][b])
    for (int idx = tid; idx < NPB * KK * HB; idx += 512) {
        const int n = idx >> 8, rem = idx & 255, k = rem >> 4, b = rem & 15;
        ush[idx] = u[(size_t)(bbase + b) * (NN * KK) + (size_t)(n0 + n) * KK + k];
    }
    __syncthreads();

    // per-thread W column base: W[n0][0][c0..c0+3]
    const float* wp = W + (size_t)n0 * WT + c0;

    float opart[8][4];
#pragma unroll
    for (int bb = 0; bb < 8; ++bb)
#pragma unroll
        for (int m = 0; m < 4; ++m) opart[bb][m] = 0.f;

    for (int nn = 0; nn < NPB; ++nn) {
        const float* un = &ush[nn << 8];

        float accU[8][4];
#pragma unroll
        for (int bb = 0; bb < 8; ++bb)
#pragma unroll
            for (int m = 0; m < 4; ++m) accU[bb][m] = 0.f;

#pragma unroll
        for (int k = 0; k < KK; ++k) {
            const float4 w  = *(const float4*)(wp + k * NCOL);  // global, coalesced
            // LDS broadcast reads (same addr across the wave -> free)
            const float4 ua = *(const float4*)&un[(k << 4) + b0];
            const float4 ub = *(const float4*)&un[(k << 4) + b0 + 4];
            float us[8];
            us[0] = ua.x; us[1] = ua.y; us[2] = ua.z; us[3] = ua.w;
            us[4] = ub.x; us[5] = ub.y; us[6] = ub.z; us[7] = ub.w;
#pragma unroll
            for (int bb = 0; bb < 8; ++bb) {
                accU[bb][0] = fmaf(us[bb], w.x, accU[bb][0]);
                accU[bb][1] = fmaf(us[bb], w.y, accU[bb][1]);
                accU[bb][2] = fmaf(us[bb], w.z, accU[bb][2]);
                accU[bb][3] = fmaf(us[bb], w.w, accU[bb][3]);
            }
        }
        wp += WT;   // next n's tile

        // ---- logits: dot with onorm (L2-resident), reduce over jq lanes ----
#pragma unroll
        for (int bb = 0; bb < 8; ++bb) {
            const float4 on4 = *(const float4*)(
                onorm + ((size_t)(bbase + b0 + bb) * CC + i0) * DD + (jq << 2));
            float p = accU[bb][0] * on4.x + accU[bb][1] * on4.y
                    + accU[bb][2] * on4.z + accU[bb][3] * on4.w;
            p += __shfl_xor(p, 1);
            p += __shfl_xor(p, 2);
            p += __shfl_xor(p, 4);
            if (jq == 0)
                logit_sh[(b0 + bb) * CC + i0] = p;
        }
        __syncthreads();   // (B) logits ready

        // ---- softmax over capsules: all 512 threads, (b = tid>>5, cap = tid&31) ----
        {
            const int b  = tid >> 5;
            const int ii = tid & 31;
            float l = logit_sh[b * CC + ii];
            float mx = l;
#pragma unroll
            for (int msk = 16; msk >= 1; msk >>= 1)
                mx = fmaxf(mx, __shfl_xor(mx, msk));
            const float e = __expf(l - mx);
            float sm = e;
#pragma unroll
            for (int msk = 16; msk >= 1; msk >>= 1)
                sm += __shfl_xor(sm, msk);
            c_sh[b * CC + ii] = e / sm;
        }
        __syncthreads();   // (C) c ready

        // ---- opart += c * U ----
#pragma unroll
        for (int bb = 0; bb < 8; ++bb) {
            const float cc = c_sh[(b0 + bb) * CC + i0];
#pragma unroll
            for (int m = 0; m < 4; ++m)
                opart[bb][m] = fmaf(cc, accU[bb][m], opart[bb][m]);
        }
    }

    // flush partials, coalesced float4 stores (this block's 16-b half)
    float* my = part + (size_t)ngrp * OSZ + (size_t)bbase * NCOL;
#pragma unroll
    for (int bb = 0; bb < 8; ++bb) {
        float4 v;
        v.x = opart[bb][0]; v.y = opart[bb][1];
        v.z = opart[bb][2]; v.w = opart[bb][3];
        *(float4*)&my[(b0 + bb) * NCOL + c0] = v;
    }
}

// Level-1 reduce: 256 partial images -> NSLICE slice images (32 each).
__global__ __launch_bounds__(256) void caps_reduce1(
    const float* __restrict__ part, float* __restrict__ ws2)
{
    const int gid   = blockIdx.x * 256 + threadIdx.x;     // 0..65535
    const int slice = gid >> 13;                          // 0..7
    const int q     = gid & 8191;                         // col-quad
    float4 acc = make_float4(0.f, 0.f, 0.f, 0.f);
    const float* p = part + ((size_t)slice * 32) * OSZ + (q << 2);
#pragma unroll 8
    for (int j = 0; j < 32; ++j) {
        const float4 v = *(const float4*)(p + (size_t)j * OSZ);
        acc.x += v.x; acc.y += v.y; acc.z += v.z; acc.w += v.w;
    }
    *(float4*)(ws2 + ((size_t)gid << 2)) = acc;
}

// Level-2 reduce + row op. mode 0: l2-normalize. mode 1: squash.
__global__ __launch_bounds__(256) void caps_reduce2(
    const float* __restrict__ ws2, float* __restrict__ dst, int mode)
{
    const int q = blockIdx.x * 256 + threadIdx.x;         // 0..8191
    float4 acc = make_float4(0.f, 0.f, 0.f, 0.f);
#pragma unroll
    for (int s = 0; s < NSLICE; ++s) {
        const float4 v = *(const float4*)(ws2 + ((size_t)s << 15) + (q << 2));
        acc.x += v.x; acc.y += v.y; acc.z += v.z; acc.w += v.w;
    }
    float s2 = acc.x * acc.x + acc.y * acc.y + acc.z * acc.z + acc.w * acc.w;
    s2 += __shfl_xor(s2, 1);
    s2 += __shfl_xor(s2, 2);
    s2 += __shfl_xor(s2, 4);
    float scale;
    if (mode == 0) {
        scale = rsqrtf(fmaxf(s2, 1e-12f));
    } else {
        scale = (s2 / (1.f + s2)) / sqrtf(s2 + 1e-7f);
    }
    float4 o;
    o.x = acc.x * scale; o.y = acc.y * scale;
    o.z = acc.z * scale; o.w = acc.w * scale;
    *(float4*)(dst + ((size_t)q << 2)) = o;
}

extern "C" void kernel_launch(void* const* d_in, const int* in_sizes, int n_in,
                              void* d_out, int out_size, void* d_ws, size_t ws_size,
                              hipStream_t stream)
{
    const float* u = (const float*)d_in[0];   // (32, 2048, 16)
    const float* W = (const float*)d_in[1];   // (2048, 16, 1024)
    float* out = (float*)d_out;               // (32, 32, 32)

    // ws layout: part (256*32768 fl = 32 MB) | ws2 (1 MB) | onorm (128 KB)
    float* part  = (float*)d_ws;
    float* ws2   = part + (size_t)NGRP * OSZ;
    float* onorm = ws2 + (size_t)NSLICE * OSZ;

    // onorm = 0 => logits 0 => softmax uniform 1/32 (exactly iteration 0)
    hipMemsetAsync(onorm, 0, (size_t)OSZ * sizeof(float), stream);

    for (int it = 0; it < 3; ++it) {
        caps_stage<<<2 * NGRP, 512, 0, stream>>>(u, W, onorm, part);
        caps_reduce1<<<256, 256, 0, stream>>>(part, ws2);
        if (it < 2)
            caps_reduce2<<<32, 256, 0, stream>>>(ws2, onorm, 0);  // l2-normalize
        else
            caps_reduce2<<<32, 256, 0, stream>>>(ws2, out, 1);    // squash -> d_out
    }
}

// Round 7
// 410.591 us; speedup vs baseline: 5.7807x; 1.6042x over previous
//
#include <hip/hip_runtime.h>
#include <math.h>
#include <stdint.h>

// Problem constants
#define BB   32     // batch
#define NN   2048   // input capsules
#define KK   16     // input dim
#define CC   32     // output capsules
#define DD   32     // capsule dim
#define NCOL 1024   // CC*DD
#define NPB  8      // n per block -> 256 blocks = 1/CU
#define WT   (KK * NCOL)          // 16384 floats = one 64 KB W tile
#define OSZ  (BB * NCOL)          // 32768 floats = one full o/partial image
#define NGRP (NN / NPB)           // 256 partial images
#define NSLICE 8                  // reduce tree fan-in stage 1: 256 -> 8

// Ladder (R0..R6):
//  - 1024-thr blocks: hard 64-VGPR pin (4x). LDS-staged W: barrier-coupled
//    DMA serializes (R0 95us / R3 148us). Direct-W at 64 VGPR: spills GBs
//    (R4/R5). R6 (direct-W, 512thr, waves_per_eu(2)) hit both gates
//    (VGPR=128, no spill) but was LATENCY-bound at 190us: the TWO BLOCK
//    BARRIERS per n-iter (needed only to share softmax across bg halves)
//    re-serialize the load pipeline every iteration; occupancy 21%,
//    VALUBusy 12%, hbm 1.5 TB/s — nothing saturated.
// R7 (this): make the routing iteration WAVE-AUTONOMOUS. One wave owns
// 4 b's x ALL 32 caps x ALL 32 d's: lane=(octet,dq), quad-group j
// covers cap = oct+8j at cols 4*lane+256*j. Logit dot reduces via octet
// shuffles (1,2,4); softmax max/sum via cross-octet shuffles (8,16,32).
// ZERO barriers in the main loop — waves free-run, each n exposes 64
// independent coalesced float4 W loads for the compiler to pipeline.
// accU[4][4][4]+opart[4][4][4]=128 acc floats => ~180 VGPR demand; the
// waves_per_eu(2) attribute grants up to 256 (R6-proven path). 8-wave
// block = all 32 b's => W ranges disjoint across blocks (no XCD games);
// intra-block 8-wave W redundancy is L1/L2-served. 256 blocks = 1/CU,
// 2 waves/SIMD, matching the VGPR occupancy exactly.
__global__ __launch_bounds__(512) __attribute__((amdgpu_waves_per_eu(2)))
void caps_stage(const float* __restrict__ u, const float* __restrict__ W,
                const float* __restrict__ onorm, float* __restrict__ part)
{
    __shared__ float ush[NPB * KK * BB];   // 16 KB: [n][k][b], all 32 b's

    const int tid  = threadIdx.x;
    const int wv   = tid >> 6;         // wave 0..7
    const int lane = tid & 63;
    const int oct  = lane >> 3;        // octet 0..7 (capsule group)
    const int dq   = lane & 7;         // d-quad within capsule
    const int b0   = wv << 2;          // this wave's 4 batches (global)
    const int n0   = blockIdx.x * NPB;

    // stage u (16 KB once): consecutive lanes along k -> coalesced 64B rows
    for (int idx = tid; idx < NPB * KK * BB; idx += 512) {
        const int k = idx & 15, b = (idx >> 4) & 31, n = idx >> 9;
        ush[(n << 9) + (k << 5) + b] =
            u[(size_t)b * (NN * KK) + (size_t)(n0 + n) * KK + k];
    }
    __syncthreads();   // the ONLY barrier in the kernel

    // per-lane W base: cols 4*lane (+256*j for quad-group j)
    const float* wp = W + (size_t)n0 * WT + (lane << 2);

    float opart[4][4][4];              // [b][j][e]
#pragma unroll
    for (int b = 0; b < 4; ++b)
#pragma unroll
        for (int j = 0; j < 4; ++j)
#pragma unroll
            for (int e = 0; e < 4; ++e) opart[b][j][e] = 0.f;

    for (int nn = 0; nn < NPB; ++nn) {
        const float* un = &ush[nn << 9];   // [k][b] 16x32

        float accU[4][4][4];
#pragma unroll
        for (int b = 0; b < 4; ++b)
#pragma unroll
            for (int j = 0; j < 4; ++j)
#pragma unroll
                for (int e = 0; e < 4; ++e) accU[b][j][e] = 0.f;

#pragma unroll
        for (int k = 0; k < KK; ++k) {
            // 4 coalesced float4 W loads (64 indep loads per n -> deep pipeline)
            const float4 w0 = *(const float4*)(wp + k * NCOL);
            const float4 w1 = *(const float4*)(wp + k * NCOL + 256);
            const float4 w2 = *(const float4*)(wp + k * NCOL + 512);
            const float4 w3 = *(const float4*)(wp + k * NCOL + 768);
            const float4 ub = *(const float4*)&un[(k << 5) + b0];  // LDS broadcast
            const float us[4] = {ub.x, ub.y, ub.z, ub.w};
#pragma unroll
            for (int b = 0; b < 4; ++b) {
                accU[b][0][0] = fmaf(us[b], w0.x, accU[b][0][0]);
                accU[b][0][1] = fmaf(us[b], w0.y, accU[b][0][1]);
                accU[b][0][2] = fmaf(us[b], w0.z, accU[b][0][2]);
                accU[b][0][3] = fmaf(us[b], w0.w, accU[b][0][3]);
                accU[b][1][0] = fmaf(us[b], w1.x, accU[b][1][0]);
                accU[b][1][1] = fmaf(us[b], w1.y, accU[b][1][1]);
                accU[b][1][2] = fmaf(us[b], w1.z, accU[b][1][2]);
                accU[b][1][3] = fmaf(us[b], w1.w, accU[b][1][3]);
                accU[b][2][0] = fmaf(us[b], w2.x, accU[b][2][0]);
                accU[b][2][1] = fmaf(us[b], w2.y, accU[b][2][1]);
                accU[b][2][2] = fmaf(us[b], w2.z, accU[b][2][2]);
                accU[b][2][3] = fmaf(us[b], w2.w, accU[b][2][3]);
                accU[b][3][0] = fmaf(us[b], w3.x, accU[b][3][0]);
                accU[b][3][1] = fmaf(us[b], w3.y, accU[b][3][1]);
                accU[b][3][2] = fmaf(us[b], w3.z, accU[b][3][2]);
                accU[b][3][3] = fmaf(us[b], w3.w, accU[b][3][3]);
            }
        }
        wp += WT;   // next n's tile

        // ---- wave-local logits + softmax (no LDS, no barriers) ----
        float cv[4][4];
#pragma unroll
        for (int b = 0; b < 4; ++b) {
            float L[4];
#pragma unroll
            for (int j = 0; j < 4; ++j) {
                // cap = oct + 8j; onorm dot over this lane's 4 d's
                const float4 on4 = *(const float4*)(
                    onorm + ((size_t)(b0 + b) * CC + oct + (j << 3)) * DD + (dq << 2));
                float p = accU[b][j][0] * on4.x + accU[b][j][1] * on4.y
                        + accU[b][j][2] * on4.z + accU[b][j][3] * on4.w;
                p += __shfl_xor(p, 1);     // octet-internal: sum 8 d-quads
                p += __shfl_xor(p, 2);
                p += __shfl_xor(p, 4);
                L[j] = p;
            }
            // softmax over 32 caps: per-lane max over j, then across octets
            float mx = fmaxf(fmaxf(L[0], L[1]), fmaxf(L[2], L[3]));
            mx = fmaxf(mx, __shfl_xor(mx, 8));
            mx = fmaxf(mx, __shfl_xor(mx, 16));
            mx = fmaxf(mx, __shfl_xor(mx, 32));
            float s = 0.f;
#pragma unroll
            for (int j = 0; j < 4; ++j) { L[j] = __expf(L[j] - mx); s += L[j]; }
            s += __shfl_xor(s, 8);
            s += __shfl_xor(s, 16);
            s += __shfl_xor(s, 32);
            const float inv = 1.f / s;
#pragma unroll
            for (int j = 0; j < 4; ++j) cv[b][j] = L[j] * inv;
        }

        // ---- opart += c * U ----
#pragma unroll
        for (int b = 0; b < 4; ++b)
#pragma unroll
            for (int j = 0; j < 4; ++j)
#pragma unroll
                for (int e = 0; e < 4; ++e)
                    opart[b][j][e] = fmaf(cv[b][j], accU[b][j][e], opart[b][j][e]);
    }

    // flush partials: float4 at col 256*j + 4*lane -> coalesced
    float* my = part + (size_t)blockIdx.x * OSZ + (size_t)b0 * NCOL + (lane << 2);
#pragma unroll
    for (int b = 0; b < 4; ++b)
#pragma unroll
        for (int j = 0; j < 4; ++j) {
            float4 v;
            v.x = opart[b][j][0]; v.y = opart[b][j][1];
            v.z = opart[b][j][2]; v.w = opart[b][j][3];
            *(float4*)&my[b * NCOL + (j << 8)] = v;
        }
}

// Level-1 reduce: 256 partial images -> NSLICE slice images (32 each).
__global__ __launch_bounds__(256) void caps_reduce1(
    const float* __restrict__ part, float* __restrict__ ws2)
{
    const int gid   = blockIdx.x * 256 + threadIdx.x;     // 0..65535
    const int slice = gid >> 13;                          // 0..7
    const int q     = gid & 8191;                         // col-quad
    float4 acc = make_float4(0.f, 0.f, 0.f, 0.f);
    const float* p = part + ((size_t)slice * 32) * OSZ + (q << 2);
#pragma unroll 8
    for (int j = 0; j < 32; ++j) {
        const float4 v = *(const float4*)(p + (size_t)j * OSZ);
        acc.x += v.x; acc.y += v.y; acc.z += v.z; acc.w += v.w;
    }
    *(float4*)(ws2 + ((size_t)gid << 2)) = acc;
}

// Level-2 reduce + row op. mode 0: l2-normalize. mode 1: squash.
__global__ __launch_bounds__(256) void caps_reduce2(
    const float* __restrict__ ws2, float* __restrict__ dst, int mode)
{
    const int q = blockIdx.x * 256 + threadIdx.x;         // 0..8191
    float4 acc = make_float4(0.f, 0.f, 0.f, 0.f);
#pragma unroll
    for (int s = 0; s < NSLICE; ++s) {
        const float4 v = *(const float4*)(ws2 + ((size_t)s << 15) + (q << 2));
        acc.x += v.x; acc.y += v.y; acc.z += v.z; acc.w += v.w;
    }
    float s2 = acc.x * acc.x + acc.y * acc.y + acc.z * acc.z + acc.w * acc.w;
    s2 += __shfl_xor(s2, 1);
    s2 += __shfl_xor(s2, 2);
    s2 += __shfl_xor(s2, 4);
    float scale;
    if (mode == 0) {
        scale = rsqrtf(fmaxf(s2, 1e-12f));
    } else {
        scale = (s2 / (1.f + s2)) / sqrtf(s2 + 1e-7f);
    }
    float4 o;
    o.x = acc.x * scale; o.y = acc.y * scale;
    o.z = acc.z * scale; o.w = acc.w * scale;
    *(float4*)(dst + ((size_t)q << 2)) = o;
}

extern "C" void kernel_launch(void* const* d_in, const int* in_sizes, int n_in,
                              void* d_out, int out_size, void* d_ws, size_t ws_size,
                              hipStream_t stream)
{
    const float* u = (const float*)d_in[0];   // (32, 2048, 16)
    const float* W = (const float*)d_in[1];   // (2048, 16, 1024)
    float* out = (float*)d_out;               // (32, 32, 32)

    // ws layout: part (256*32768 fl = 32 MB) | ws2 (1 MB) | onorm (128 KB)
    float* part  = (float*)d_ws;
    float* ws2   = part + (size_t)NGRP * OSZ;
    float* onorm = ws2 + (size_t)NSLICE * OSZ;

    // onorm = 0 => logits 0 => softmax uniform 1/32 (exactly iteration 0)
    hipMemsetAsync(onorm, 0, (size_t)OSZ * sizeof(float), stream);

    for (int it = 0; it < 3; ++it) {
        caps_stage<<<NGRP, 512, 0, stream>>>(u, W, onorm, part);
        caps_reduce1<<<256, 256, 0, stream>>>(part, ws2);
        if (it < 2)
            caps_reduce2<<<32, 256, 0, stream>>>(ws2, onorm, 0);  // l2-normalize
        else
            caps_reduce2<<<32, 256, 0, stream>>>(ws2, out, 1);    // squash -> d_out
    }
}